// Round 7
// baseline (9827.171 us; speedup 1.0000x reference)
//
#include <hip/hip_runtime.h>
#include <math.h>

// ---------------------------------------------------------------------------
// BiLSTM-CRF tagger on MI355X.
//   T=2048, D=512, H=512, HD=256, L=2, NTAGS=20, START=18, END=19
//
// R1:  spinning agent-acquire loads -> 7.3ms recur (cache-inv storm).
// R3:  release/acquire slots -> 6.2ms (agent fence = L2 wb+inv per step).
// R4:  fence-free seqlock (tag<<32|payload, relaxed agent atomic) -> 3.58ms.
// R5:  sc0-LOAD seqlock -> HANG (load served from own L1 -> stale spin).
// R6:  rd_l2 = atomic RMW w/ return (executes AT the XCD L2); probe elects
//      same-XCD octet; fallback R4. 3.45ms.
// R7:  single-WG register residency: impossible (CU VGPR < Whh). 90ms.
// R8:  launch_bounds(256,1): no effect (VGPR 84). 2nd arg is a MINIMUM.
// R9:  per-consumer replicated 64B slots: write amplification catastrophe
//      (650KB/step dirty-line writeback, 9.25ms). Packed data is mandatory.
// R11: waves_per_eu(1,1)+pin: VGPR 84->132, BANK_CONFLICT 1.7e7->0, dur
//      UNCHANGED (3.6ms). FALSIFIED compute-side theories: FMA/LDS/weights
//      are fully hidden. The whole 4000cy/step is the comm chain, and the
//      dominant term must be RMW serialization: 56 poll streams per packed
//      data line x ~3 iters ~ 2000+cy.
// R12 (this): flag+ring protocol on the use_l2 path.
//      - Producers: 32 packed stores (4 lines) -> vmcnt(0) -> ONE flag
//        store (8 flags, 64B-exclusive).
//      - Consumers: rd_l2-poll FLAGS only (1 lane/wave/flag -> 7 streams
//        per flag line vs 56 per data line); then PLAIN coalesced loads of
//        the packed data (reads don't serialize like RMWs).
//      - L1 staleness beaten structurally: 32-slot ring (64KB/dir) ->
//        slot returns after 32 steps >> L1 turnover -> guaranteed miss ->
//        fresh L2 fill. Per-entry tags + rd_l2 fallback keep correctness
//        independent of the fast path. Write traffic stays packed/R6-level.
//      Agent fallback (probe fail) = R4 seqlock verbatim.
// Predict: recur 3.6 -> ~1.5-2.2ms; WRITE/FETCH unchanged; else the floor
// is the intrinsic serial chain, not contention.
// ---------------------------------------------------------------------------

#define T_LEN 2048
#define DMODEL 512
#define HD 256
#define NTAGS 20
#define START_TAG 18
#define END_TAG 19
#define NCAND 64    // candidate WGs per direction for the election
#define RING 32     // h-ring depth (64KB/dir): beats L1 lifetime, L2-tiny

__device__ __forceinline__ float fsig(float x) {
  return 1.0f / (1.0f + __expf(-x));
}
__device__ __forceinline__ float ftanh(float x) {
  float xc = fminf(15.0f, fmaxf(-15.0f, x));
  float e = __expf(2.0f * xc);
  return (e - 1.0f) / (e + 1.0f);
}

// Read current L2 content (bypasses L1 by construction: atomic RMW executes
// at the coherence point). sc0 = return old value on gfx950.
__device__ __forceinline__ unsigned long long rd_l2(unsigned long long* p) {
  unsigned long long old;
  unsigned long long zero = 0;
  asm volatile("global_atomic_add_x2 %0, %1, %2, off sc0\n\ts_waitcnt vmcnt(0)"
               : "=&v"(old)
               : "v"(p), "v"(zero)
               : "memory");
  return old;
}
// Producer publish: plain store; CDNA L1 is write-through so this reaches the
// XCD-shared L2 without any cache-maintenance ops.
__device__ __forceinline__ void pub_l2(unsigned long long* p,
                                       unsigned long long v) {
  *(volatile unsigned long long*)p = v;
}

// ---------------------------------------------------------------------------
// 1. Embedding gather: x0[t][:] = emb[sentence[t]][:]
// ---------------------------------------------------------------------------
__global__ void embed_k(const int* __restrict__ sent,
                        const float* __restrict__ emb,
                        float* __restrict__ x0) {
  int t = blockIdx.x;
  int tid = threadIdx.x;  // 0..127
  int tok = sent[t];
  const float4* src = (const float4*)(emb + (size_t)tok * DMODEL);
  float4* dst = (float4*)(x0 + (size_t)t * DMODEL);
  dst[tid] = src[tid];
}

// ---------------------------------------------------------------------------
// 2. xg GEMM: out[t][n] = sum_k X[t][k] * W[n][k] + b[n]
//    X: [2048][512], W: [1024][512], out: [2048][1024]
// 128x128 block tile, 8x8 per thread, k-tile 16.
// grid: (N/128=8, M/128=16, 2 dirs), block 256
// ---------------------------------------------------------------------------
__global__ __launch_bounds__(256) void gemm_xg_k(
    const float* __restrict__ X,
    const float* __restrict__ Wf, const float* __restrict__ Wb,
    const float* __restrict__ bf, const float* __restrict__ bb,
    float* __restrict__ outf, float* __restrict__ outb) {
  int bx = blockIdx.x;   // N tile (0..7)
  int by = blockIdx.y;   // M tile (0..15)
  int dir = blockIdx.z;
  const float* W = dir ? Wb : Wf;
  const float* bias = dir ? bb : bf;
  float* out = dir ? outb : outf;

  __shared__ __align__(16) float Xs[16][132];
  __shared__ __align__(16) float Ws[16][132];

  int tid = threadIdx.x;
  int tx = tid & 15;   // 0..15 -> N
  int ty = tid >> 4;   // 0..15 -> M

  float acc[8][8];
#pragma unroll
  for (int i = 0; i < 8; i++)
#pragma unroll
    for (int j = 0; j < 8; j++) acc[i][j] = 0.0f;

  for (int kt = 0; kt < DMODEL / 16; kt++) {
    __syncthreads();
#pragma unroll
    for (int l = 0; l < 2; l++) {
      int fi = tid + l * 256;        // 0..511  (128 rows x 4 float4)
      int row = fi >> 2;
      int kq = fi & 3;
      float4 xv = *(const float4*)(X + (size_t)(by * 128 + row) * DMODEL + kt * 16 + kq * 4);
      Xs[kq * 4 + 0][row] = xv.x;
      Xs[kq * 4 + 1][row] = xv.y;
      Xs[kq * 4 + 2][row] = xv.z;
      Xs[kq * 4 + 3][row] = xv.w;
      float4 wv = *(const float4*)(W + (size_t)(bx * 128 + row) * DMODEL + kt * 16 + kq * 4);
      Ws[kq * 4 + 0][row] = wv.x;
      Ws[kq * 4 + 1][row] = wv.y;
      Ws[kq * 4 + 2][row] = wv.z;
      Ws[kq * 4 + 3][row] = wv.w;
    }
    __syncthreads();
#pragma unroll
    for (int k = 0; k < 16; k++) {
      float4 a0 = *(const float4*)&Xs[k][ty * 4];
      float4 a1 = *(const float4*)&Xs[k][64 + ty * 4];
      float4 b0 = *(const float4*)&Ws[k][tx * 4];
      float4 b1 = *(const float4*)&Ws[k][64 + tx * 4];
      float a[8] = {a0.x, a0.y, a0.z, a0.w, a1.x, a1.y, a1.z, a1.w};
      float b[8] = {b0.x, b0.y, b0.z, b0.w, b1.x, b1.y, b1.z, b1.w};
#pragma unroll
      for (int i = 0; i < 8; i++)
#pragma unroll
        for (int j = 0; j < 8; j++) acc[i][j] += a[i] * b[j];
    }
  }

  float4 bv0 = *(const float4*)(bias + bx * 128 + tx * 4);
  float4 bv1 = *(const float4*)(bias + bx * 128 + 64 + tx * 4);
  float bb8[8] = {bv0.x, bv0.y, bv0.z, bv0.w, bv1.x, bv1.y, bv1.z, bv1.w};
#pragma unroll
  for (int i = 0; i < 8; i++) {
    int row = by * 128 + ((i < 4) ? (ty * 4 + i) : (64 + ty * 4 + (i - 4)));
    float4 o0 = {acc[i][0] + bb8[0], acc[i][1] + bb8[1], acc[i][2] + bb8[2], acc[i][3] + bb8[3]};
    float4 o1 = {acc[i][4] + bb8[4], acc[i][5] + bb8[5], acc[i][6] + bb8[6], acc[i][7] + bb8[7]};
    *(float4*)(out + (size_t)row * 1024 + bx * 128 + tx * 4) = o0;
    *(float4*)(out + (size_t)row * 1024 + bx * 128 + 64 + tx * 4) = o1;
  }
}

// ---------------------------------------------------------------------------
// 3/5. Recurrence. grid: (NCAND=64 candidates, 2 dirs), block 256.
// a) Election (R6, proven). b) Coherence probe (R6, proven).
// c) Steady state (use_l2): FMA -> shfl -> zbuf -> sync -> gates (tid<32)
//    -> 32 packed ring stores + vmcnt(0) + 1 flag store -> waves rd_l2-poll
//    their 2 flags (lanes 0,1) -> plain coalesced data loads, tag-checked,
//    rd_l2 fallback on staleness -> hbuf -> sync. Ring of 32 slots defeats
//    L1 staleness; flags are the only polled (RMW) lines.
// Agent fallback (probe failed): R4 packed parity seqlock verbatim.
// ---------------------------------------------------------------------------
__attribute__((amdgpu_waves_per_eu(1, 1)))
__global__ __launch_bounds__(256) void recur_k(
    const float* __restrict__ xg_f, const float* __restrict__ xg_b,
    const float* __restrict__ Whh_f, const float* __restrict__ Whh_b,
    const float* __restrict__ bhh_f, const float* __restrict__ bhh_b,
    float* __restrict__ xnext,
    unsigned long long* __restrict__ hcomm_fb_base,
    unsigned long long* __restrict__ ring_base,
    unsigned long long* __restrict__ flags_base,
    int* __restrict__ elect_base, unsigned long long* __restrict__ probe_base,
    int* __restrict__ vote_base) {
  int dir = blockIdx.y;         // 0=f, 1=b
  int tid = threadIdx.x;        // 0..255

  // ---- a) election -------------------------------------------------------
  int xcd;
  asm volatile("s_getreg_b32 %0, hwreg(HW_REG_XCC_ID)" : "=s"(xcd));
  xcd &= 7;
  int* cnt = elect_base + dir * (1 + NCAND);
  int* tab = cnt + 1;

  __shared__ int e_tab[NCAND];
  __shared__ int e_info[4];   // [0]=ticket, [1]=sel, [2]=kc, [3]=use_l2
  __shared__ int probe_ok[8];
  if (tid == 0) {
    int ticket = __hip_atomic_fetch_add(cnt, 1, __ATOMIC_RELAXED,
                                        __HIP_MEMORY_SCOPE_AGENT);
    __hip_atomic_store(&tab[ticket], xcd + 1, __ATOMIC_RELAXED,
                       __HIP_MEMORY_SCOPE_AGENT);
    e_info[0] = ticket;
  }
  if (tid < NCAND) {
    int v;
    do {
      v = __hip_atomic_load(&tab[tid], __ATOMIC_RELAXED,
                            __HIP_MEMORY_SCOPE_AGENT);
    } while (v == 0);
    e_tab[tid] = v - 1;
  }
  __syncthreads();
  if (tid == 0) {
    int ticket = e_info[0];
    int counts[8] = {0, 0, 0, 0, 0, 0, 0, 0};
    int home = -1;
    for (int i = 0; i < NCAND; i++) {
      int x = e_tab[i];
      counts[x]++;
      if (counts[x] == 8 && home < 0) home = x;
    }
    int sel = 0, kc = 0, probe = 0;
    if (home >= 0) {
      if (xcd == home) {
        int rank = 0;
        for (int i = 0; i < ticket; i++)
          if (e_tab[i] == home) rank++;
        if (rank < 8) { sel = 1; kc = rank; probe = 1; }
      }
    } else {
      if (ticket < 8) { sel = 1; kc = ticket; probe = 0; }
    }
    e_info[1] = sel; e_info[2] = kc; e_info[3] = probe;
  }
  __syncthreads();
  if (!e_info[1]) return;      // not selected: exit before loading weights
  int kc = e_info[2];
  int do_probe = e_info[3];
  int use_l2 = 0;

  // ---- b) coherence probe (bounded; decision via proven agent path) ------
  if (do_probe) {
    unsigned long long* probe = probe_base + (size_t)dir * 8 * 16;  // 128B/slot
    int* vote = vote_base + dir * 8;
    if (tid == 0) {
      pub_l2(&probe[kc * 16], 0xBEEF000000000000ull + (unsigned)kc);
    }
    if (tid < 8) {
      int found = 0;
      for (int iter = 0; iter < 3000 && !found; ++iter) {
        if (rd_l2(&probe[tid * 16]) ==
            0xBEEF000000000000ull + (unsigned)tid) found = 1;
      }
      probe_ok[tid] = found;
    }
    __syncthreads();
    if (tid == 0) {
      int ok = 1;
      for (int i = 0; i < 8; i++) ok &= probe_ok[i];
      // publish vote (1=fail, 2=pass) over the RELIABLE agent path
      __hip_atomic_store(&vote[kc], 1 + ok, __ATOMIC_RELAXED,
                         __HIP_MEMORY_SCOPE_AGENT);
    }
    if (tid < 8) {
      int v;
      do {
        v = __hip_atomic_load(&vote[tid], __ATOMIC_RELAXED,
                              __HIP_MEMORY_SCOPE_AGENT);
      } while (v == 0);   // bounded publishers => terminates
      probe_ok[tid] = v;
    }
    __syncthreads();
    if (tid == 0) {
      int all2 = 1;
      for (int i = 0; i < 8; i++) all2 &= (probe_ok[i] == 2);
      e_info[3] = all2;
    }
    __syncthreads();
    use_l2 = e_info[3];
  }

  // ---- c) setup ----------------------------------------------------------
  const float* Whh = dir ? Whh_b : Whh_f;
  const float* bhh = dir ? bhh_b : bhh_f;
  const float* xg = dir ? xg_b : xg_f;
  unsigned long long* hcomm_fb = hcomm_fb_base + (size_t)dir * 2 * HD;
  unsigned long long* ring = ring_base + (size_t)dir * RING * HD;
  unsigned long long* flags = flags_base + (size_t)dir * 64;  // 8 flags x 64B

  int r = tid >> 1;             // local row 0..127
  int half = tid & 1;           // which 128-col half
  int g = r >> 5;               // gate 0..3 (i,f,g,o)
  int kl = r & 31;
  int grow = g * 256 + kc * 32 + kl;  // global gate row 0..1023

  // Load weights and PIN them in VGPRs (R11: VGPR 132, conflicts 0 --
  // compute is fully hidden; keep as-is).
  float4 Wv[32];
  const float4* wrow = (const float4*)(Whh + (size_t)grow * HD + half * 128);
#pragma unroll
  for (int j = 0; j < 32; j++) Wv[j] = wrow[j];
#pragma unroll
  for (int j = 0; j < 32; j++) {
    asm volatile("" : "+v"(Wv[j].x), "+v"(Wv[j].y), "+v"(Wv[j].z),
                      "+v"(Wv[j].w));
  }
  float bias = bhh[grow];

  // h_{t-1}: two 128-float halves padded by +8 floats.
  __shared__ __align__(16) float hbuf[272];
  __shared__ float zbuf[128];
  hbuf[tid] = 0.0f;
  if (tid < 16) hbuf[256 + tid] = 0.0f;
  __syncthreads();

  float c = 0.0f;               // cell state, used by tid<32
  bool is_remote = ((tid >> 5) != kc);  // this thread fills entry `tid`

  // xg prefetch, one full step ahead
  float xgv_next = 0.0f;
  {
    int t0 = dir ? (T_LEN - 1) : 0;
    if (!half) xgv_next = xg[(size_t)t0 * 1024 + grow];
  }

#pragma unroll 1
  for (int it = 0; it < T_LEN; ++it) {
    int t = dir ? (T_LEN - 1 - it) : it;
    int p = it & 1;
    unsigned int tag = (unsigned)(it + 1);
    unsigned long long* rs = ring + (size_t)(it & (RING - 1)) * HD;

    float xgv = xgv_next;
    if (it + 1 < T_LEN) {
      int tn = dir ? (T_LEN - 2 - it) : (it + 1);
      if (!half) xgv_next = xg[(size_t)tn * 1024 + grow];
    }

    const float4* h4 = (const float4*)hbuf + half * 34;  // 34 = (128+8)/4
    float4 acc = {0.f, 0.f, 0.f, 0.f};
#pragma unroll
    for (int j = 0; j < 32; j++) {
      float4 hv = h4[j];
      acc.x += Wv[j].x * hv.x;
      acc.y += Wv[j].y * hv.y;
      acc.z += Wv[j].z * hv.z;
      acc.w += Wv[j].w * hv.w;
    }
    float s = (acc.x + acc.y) + (acc.z + acc.w);
    s += __shfl_xor(s, 1, 64);   // combine the two halves of the row
    if (!half) zbuf[r] = s + xgv + bias;
    __syncthreads();             // zbuf ready; hbuf reads of h_{t-1} done

    if (tid < 32) {
      float zi = zbuf[tid];
      float zf = zbuf[32 + tid];
      float zg = zbuf[64 + tid];
      float zo = zbuf[96 + tid];
      c = fsig(zf) * c + fsig(zi) * ftanh(zg);
      float h = fsig(zo) * ftanh(c);
      union { float f; unsigned u; } cv;
      cv.f = h;
      unsigned long long pkt = ((unsigned long long)tag << 32) | cv.u;
      int e = kc * 32 + tid;
      if (use_l2) {
        // packed ring slot: 32 entries -> 4 lines, coalesced
        pub_l2(&rs[e], pkt);
        // wave-wide drain: data committed to L2 before the flag goes out
        asm volatile("s_waitcnt vmcnt(0)" ::: "memory");
        if (tid == 0) pub_l2(&flags[kc * 8], (unsigned long long)tag);
      } else {
        __hip_atomic_store(&hcomm_fb[p * HD + e], pkt,
                           __ATOMIC_RELAXED, __HIP_MEMORY_SCOPE_AGENT);
      }
      xnext[(size_t)t * DMODEL + dir * HD + e] = h;
      hbuf[((e >> 7) * 136) + (e & 127)] = h;
    }

    if (use_l2) {
      // flag poll: lanes 0,1 of each wave poll the 2 chunks this wave needs
      // (7 RMW streams per flag line total -- contention-free vs 56/line).
      int lane = tid & 63;
      int wv = tid >> 6;
      if (lane < 2) {
        int ch = wv * 2 + lane;
        if (ch != kc) {
          unsigned long long fv;
          do { fv = rd_l2(&flags[ch * 8]); } while (fv < (unsigned long long)tag);
        }
      }
      // wave reconverges here: flags for both chunks confirmed -> data is
      // in L2. Plain coalesced load; ring depth guarantees L1 miss; tag
      // check + rd_l2 fallback keeps correctness off the fast path.
      if (is_remote) {
        unsigned long long v = *(volatile unsigned long long*)&rs[tid];
        if ((unsigned)(v >> 32) != tag) {
          do { v = rd_l2(&rs[tid]); } while ((unsigned)(v >> 32) != tag);
        }
        union { unsigned u; float f; } cv;
        cv.u = (unsigned)v;
        hbuf[((tid >> 7) * 136) + (tid & 127)] = cv.f;
      }
    } else if (is_remote) {
      unsigned long long v;
      do {
        v = __hip_atomic_load(&hcomm_fb[p * HD + tid], __ATOMIC_RELAXED,
                              __HIP_MEMORY_SCOPE_AGENT);
      } while ((unsigned)(v >> 32) != tag);
      union { unsigned u; float f; } cv;
      cv.u = (unsigned)v;
      hbuf[((tid >> 7) * 136) + (tid & 127)] = cv.f;
    }
    __syncthreads();             // full h_t assembled in LDS
  }
}

// ---------------------------------------------------------------------------
// 6. Projection: feats[t][n] = x2[t][:] . W_out[n][:] + b_out[n]
// ---------------------------------------------------------------------------
__global__ void proj_k(const float* __restrict__ x2,
                       const float* __restrict__ Wo,
                       const float* __restrict__ bo,
                       float* __restrict__ feats) {
  int t = blockIdx.x;
  int tid = threadIdx.x;
  int n = tid & 31;
  int seg = tid >> 5;   // 0..7
  __shared__ float red[8][32];
  float s = 0.0f;
  if (n < NTAGS) {
    const float* xr = x2 + (size_t)t * DMODEL + seg * 64;
    const float* wr = Wo + (size_t)n * DMODEL + seg * 64;
#pragma unroll
    for (int j = 0; j < 64; j++) s += xr[j] * wr[j];
  }
  red[seg][n] = s;
  __syncthreads();
  if (tid < NTAGS) {
    float tot = bo[tid];
#pragma unroll
    for (int k = 0; k < 8; k++) tot += red[k][tid];
    feats[(size_t)t * NTAGS + tid] = tot;
  }
}

// ---------------------------------------------------------------------------
// 7. Viterbi: single block, 64 threads (one wave).
// ---------------------------------------------------------------------------
__global__ void viterbi_k(const float* __restrict__ feats,
                          const float* __restrict__ tr,
                          float* __restrict__ out) {
  __shared__ float v[NTAGS];
  __shared__ unsigned char bp[T_LEN * NTAGS];  // 40KB
  __shared__ float term[NTAGS];
  int tid = threadIdx.x;

  float trrow[NTAGS];
  if (tid < NTAGS) {
#pragma unroll
    for (int p = 0; p < NTAGS; p++) trrow[p] = tr[tid * NTAGS + p];
    v[tid] = (tid == START_TAG) ? 0.0f : -10000.0f;
  }
  __syncthreads();

#pragma unroll 1
  for (int t = 0; t < T_LEN; t++) {
    float fv = 0.0f;
    if (tid < NTAGS) fv = feats[(size_t)t * NTAGS + tid];
    float best = -3.4e38f;
    int arg = 0;
    if (tid < NTAGS) {
#pragma unroll
      for (int p = 0; p < NTAGS; p++) {
        float sc = v[p] + trrow[p];
        if (sc > best) { best = sc; arg = p; }
      }
      bp[t * NTAGS + tid] = (unsigned char)arg;
    }
    __syncthreads();
    if (tid < NTAGS) v[tid] = best + fv;
    __syncthreads();
  }

  if (tid < NTAGS) term[tid] = v[tid] + tr[END_TAG * NTAGS + tid];
  __syncthreads();
  if (tid == 0) {
    float bs = term[0];
    int bi = 0;
    for (int p = 1; p < NTAGS; p++) {
      if (term[p] > bs) { bs = term[p]; bi = p; }
    }
    out[0] = bs;
    int tag = bi;
    for (int t = T_LEN - 1; t >= 0; t--) {
      out[1 + t] = (float)tag;
      tag = bp[t * NTAGS + tag];
    }
  }
}

// ---------------------------------------------------------------------------
// Launch
// ---------------------------------------------------------------------------
extern "C" void kernel_launch(void* const* d_in, const int* in_sizes, int n_in,
                              void* d_out, int out_size, void* d_ws, size_t ws_size,
                              hipStream_t stream) {
  const int* sent = (const int*)d_in[0];
  const float* emb = (const float*)d_in[1];
  const float* l0f_Wih = (const float*)d_in[2];
  const float* l0f_Whh = (const float*)d_in[3];
  const float* l0f_bih = (const float*)d_in[4];
  const float* l0f_bhh = (const float*)d_in[5];
  const float* l0b_Wih = (const float*)d_in[6];
  const float* l0b_Whh = (const float*)d_in[7];
  const float* l0b_bih = (const float*)d_in[8];
  const float* l0b_bhh = (const float*)d_in[9];
  const float* l1f_Wih = (const float*)d_in[10];
  const float* l1f_Whh = (const float*)d_in[11];
  const float* l1f_bih = (const float*)d_in[12];
  const float* l1f_bhh = (const float*)d_in[13];
  const float* l1b_Wih = (const float*)d_in[14];
  const float* l1b_Whh = (const float*)d_in[15];
  const float* l1b_bih = (const float*)d_in[16];
  const float* l1b_bhh = (const float*)d_in[17];
  const float* W_out = (const float*)d_in[18];
  const float* b_out = (const float*)d_in[19];
  const float* transitions = (const float*)d_in[20];

  char* ws = (char*)d_ws;
  size_t off = 0;
  float* x0 = (float*)(ws + off);  off += (size_t)T_LEN * DMODEL * 4;          // 4MB
  float* xgf = (float*)(ws + off); off += (size_t)T_LEN * 1024 * 4;            // 8MB
  float* xgb = (float*)(ws + off); off += (size_t)T_LEN * 1024 * 4;            // 8MB
  float* x1 = (float*)(ws + off);  off += (size_t)T_LEN * DMODEL * 4;          // 4MB
  float* x2 = (float*)(ws + off);  off += (size_t)T_LEN * DMODEL * 4;          // 4MB
  float* feats = (float*)(ws + off); off += (size_t)T_LEN * NTAGS * 4;

  // sync area (single contiguous memset)
  off = (off + 127) & ~(size_t)127;
  char* sync_area = ws + off;
  // per layer: fb (2 dir x 4KB) | ring (2 dir x 64KB) | flags (2 dir x 512B)
  size_t fb_b = 2 * 2 * HD * 8;            // 8KB
  size_t ring_b = 2 * (size_t)RING * HD * 8;  // 128KB
  size_t flg_b = 2 * 64 * 8;               // 1KB
  size_t layer_b = fb_b + ring_b + flg_b;  // 137KB
  char* L0 = sync_area;
  char* L1 = sync_area + layer_b;
  unsigned long long* fb0 = (unsigned long long*)(L0);
  unsigned long long* ring0 = (unsigned long long*)(L0 + fb_b);
  unsigned long long* flg0 = (unsigned long long*)(L0 + fb_b + ring_b);
  unsigned long long* fb1 = (unsigned long long*)(L1);
  unsigned long long* ring1 = (unsigned long long*)(L1 + fb_b);
  unsigned long long* flg1 = (unsigned long long*)(L1 + fb_b + ring_b);
  char* aux = sync_area + 2 * layer_b;
  int* elect0 = (int*)(aux);                                // 2KB
  int* elect1 = (int*)(aux + 2048);                         // 2KB
  unsigned long long* probe0 = (unsigned long long*)(aux + 4096);   // 2KB
  unsigned long long* probe1 = (unsigned long long*)(aux + 6144);   // 2KB
  int* vote0 = (int*)(aux + 8192);                          // 1KB
  int* vote1 = (int*)(aux + 9216);                          // 1KB
  size_t sync_bytes = 2 * layer_b + 10240;
  off += sync_bytes;

  float* outf = (float*)d_out;

  // zero all sync state (d_ws is re-poisoned to 0xAA before every launch)
  (void)hipMemsetAsync(sync_area, 0, sync_bytes, stream);

  embed_k<<<dim3(T_LEN), dim3(128), 0, stream>>>(sent, emb, x0);

  gemm_xg_k<<<dim3(8, 16, 2), dim3(256), 0, stream>>>(
      x0, l0f_Wih, l0b_Wih, l0f_bih, l0b_bih, xgf, xgb);

  recur_k<<<dim3(NCAND, 2), dim3(256), 0, stream>>>(
      xgf, xgb, l0f_Whh, l0b_Whh, l0f_bhh, l0b_bhh, x1, fb0, ring0, flg0,
      elect0, probe0, vote0);

  gemm_xg_k<<<dim3(8, 16, 2), dim3(256), 0, stream>>>(
      x1, l1f_Wih, l1b_Wih, l1f_bih, l1b_bih, xgf, xgb);

  recur_k<<<dim3(NCAND, 2), dim3(256), 0, stream>>>(
      xgf, xgb, l1f_Whh, l1b_Whh, l1f_bhh, l1b_bhh, x2, fb1, ring1, flg1,
      elect1, probe1, vote1);

  proj_k<<<dim3(T_LEN), dim3(256), 0, stream>>>(x2, W_out, b_out, feats);

  viterbi_k<<<dim3(1), dim3(64), 0, stream>>>(feats, transitions, outf);
}

// Round 8
// 8434.119 us; speedup vs baseline: 1.1652x; 1.1652x over previous
//
#include <hip/hip_runtime.h>
#include <math.h>

// ---------------------------------------------------------------------------
// BiLSTM-CRF tagger on MI355X.
//   T=2048, D=512, H=512, HD=256, L=2, NTAGS=20, START=18, END=19
//
// R1:  spinning agent-acquire loads -> 7.3ms recur (cache-inv storm).
// R4:  fence-free seqlock (tag<<32|payload, relaxed agent atomic) -> 3.58ms.
// R5:  sc0-LOAD seqlock -> HANG (load served from own L1 -> stale spin).
// R6:  rd_l2 = atomic RMW w/ return (executes AT the XCD L2); probe elects
//      same-XCD octet; fallback R4. 3.45ms. BEST comm scheme.
// R7:  single-WG register residency: impossible (CU VGPR < Whh). 90ms.
// R8/R11: VGPR cap lift + pin: VGPR 84->132, conflicts 1.7e7->0, dur
//      UNCHANGED. Compute (FMA/LDS/weights) is fully latency-hidden.
// R9:  replicated 64B slots: 9.25ms (warm-line eviction by xg stream).
//      Packed hammered-hot lines are mandatory.
// R12: flag+ring: WRITE 113->32MB (poll RMWs were the writes) but dur
//      3.59->4.89ms. Flag indirection = +2 serial L2 round trips. DIRECT
//      data-poll (sync+payload in one RMW, per-thread parallel) is optimal.
// R13 (this): R6 comm verbatim + three serial-chain cuts:
//      a) xg prefetch issued AFTER polls, 2 steps deep: rd_l2's vmcnt(0)
//         was draining the in-flight HBM prefetch inside the first poll
//         every step (~300-500cy).
//      b) gate-row remap (g=r&3, kl=r>>2): the 4 gate rows of h_kl live in
//         one 8-lane group -> gates via 3 in-wave shfls, all 4 waves
//         produce 8 h each. No zbuf, ONE barrier/step (hbuf LDS parity
//         double-buffer).
//      c) pin/waves_per_eu reverted (proven hidden); hbuf pad kept.
// Predict: recur 3.59 -> ~2.7-3.0ms; WRITE back ~113MB; else chain is
// L2-service/straggler floor -> next: 4 WGs x 512thr (halve partners).
// ---------------------------------------------------------------------------

#define T_LEN 2048
#define DMODEL 512
#define HD 256
#define NTAGS 20
#define START_TAG 18
#define END_TAG 19
#define NCAND 64    // candidate WGs per direction for the election

__device__ __forceinline__ float fsig(float x) {
  return 1.0f / (1.0f + __expf(-x));
}
__device__ __forceinline__ float ftanh(float x) {
  float xc = fminf(15.0f, fmaxf(-15.0f, x));
  float e = __expf(2.0f * xc);
  return (e - 1.0f) / (e + 1.0f);
}

// Read current L2 content (bypasses L1 by construction: atomic RMW executes
// at the coherence point). sc0 = return old value on gfx950.
__device__ __forceinline__ unsigned long long rd_l2(unsigned long long* p) {
  unsigned long long old;
  unsigned long long zero = 0;
  asm volatile("global_atomic_add_x2 %0, %1, %2, off sc0\n\ts_waitcnt vmcnt(0)"
               : "=&v"(old)
               : "v"(p), "v"(zero)
               : "memory");
  return old;
}
// Producer publish: plain store; CDNA L1 is write-through so this reaches the
// XCD-shared L2 without any cache-maintenance ops.
__device__ __forceinline__ void pub_l2(unsigned long long* p,
                                       unsigned long long v) {
  *(volatile unsigned long long*)p = v;
}

// ---------------------------------------------------------------------------
// 1. Embedding gather: x0[t][:] = emb[sentence[t]][:]
// ---------------------------------------------------------------------------
__global__ void embed_k(const int* __restrict__ sent,
                        const float* __restrict__ emb,
                        float* __restrict__ x0) {
  int t = blockIdx.x;
  int tid = threadIdx.x;  // 0..127
  int tok = sent[t];
  const float4* src = (const float4*)(emb + (size_t)tok * DMODEL);
  float4* dst = (float4*)(x0 + (size_t)t * DMODEL);
  dst[tid] = src[tid];
}

// ---------------------------------------------------------------------------
// 2. xg GEMM: out[t][n] = sum_k X[t][k] * W[n][k] + b[n]
//    X: [2048][512], W: [1024][512], out: [2048][1024]
// 128x128 block tile, 8x8 per thread, k-tile 16.
// grid: (N/128=8, M/128=16, 2 dirs), block 256
// ---------------------------------------------------------------------------
__global__ __launch_bounds__(256) void gemm_xg_k(
    const float* __restrict__ X,
    const float* __restrict__ Wf, const float* __restrict__ Wb,
    const float* __restrict__ bf, const float* __restrict__ bb,
    float* __restrict__ outf, float* __restrict__ outb) {
  int bx = blockIdx.x;   // N tile (0..7)
  int by = blockIdx.y;   // M tile (0..15)
  int dir = blockIdx.z;
  const float* W = dir ? Wb : Wf;
  const float* bias = dir ? bb : bf;
  float* out = dir ? outb : outf;

  __shared__ __align__(16) float Xs[16][132];
  __shared__ __align__(16) float Ws[16][132];

  int tid = threadIdx.x;
  int tx = tid & 15;   // 0..15 -> N
  int ty = tid >> 4;   // 0..15 -> M

  float acc[8][8];
#pragma unroll
  for (int i = 0; i < 8; i++)
#pragma unroll
    for (int j = 0; j < 8; j++) acc[i][j] = 0.0f;

  for (int kt = 0; kt < DMODEL / 16; kt++) {
    __syncthreads();
#pragma unroll
    for (int l = 0; l < 2; l++) {
      int fi = tid + l * 256;        // 0..511  (128 rows x 4 float4)
      int row = fi >> 2;
      int kq = fi & 3;
      float4 xv = *(const float4*)(X + (size_t)(by * 128 + row) * DMODEL + kt * 16 + kq * 4);
      Xs[kq * 4 + 0][row] = xv.x;
      Xs[kq * 4 + 1][row] = xv.y;
      Xs[kq * 4 + 2][row] = xv.z;
      Xs[kq * 4 + 3][row] = xv.w;
      float4 wv = *(const float4*)(W + (size_t)(bx * 128 + row) * DMODEL + kt * 16 + kq * 4);
      Ws[kq * 4 + 0][row] = wv.x;
      Ws[kq * 4 + 1][row] = wv.y;
      Ws[kq * 4 + 2][row] = wv.z;
      Ws[kq * 4 + 3][row] = wv.w;
    }
    __syncthreads();
#pragma unroll
    for (int k = 0; k < 16; k++) {
      float4 a0 = *(const float4*)&Xs[k][ty * 4];
      float4 a1 = *(const float4*)&Xs[k][64 + ty * 4];
      float4 b0 = *(const float4*)&Ws[k][tx * 4];
      float4 b1 = *(const float4*)&Ws[k][64 + tx * 4];
      float a[8] = {a0.x, a0.y, a0.z, a0.w, a1.x, a1.y, a1.z, a1.w};
      float b[8] = {b0.x, b0.y, b0.z, b0.w, b1.x, b1.y, b1.z, b1.w};
#pragma unroll
      for (int i = 0; i < 8; i++)
#pragma unroll
        for (int j = 0; j < 8; j++) acc[i][j] += a[i] * b[j];
    }
  }

  float4 bv0 = *(const float4*)(bias + bx * 128 + tx * 4);
  float4 bv1 = *(const float4*)(bias + bx * 128 + 64 + tx * 4);
  float bb8[8] = {bv0.x, bv0.y, bv0.z, bv0.w, bv1.x, bv1.y, bv1.z, bv1.w};
#pragma unroll
  for (int i = 0; i < 8; i++) {
    int row = by * 128 + ((i < 4) ? (ty * 4 + i) : (64 + ty * 4 + (i - 4)));
    float4 o0 = {acc[i][0] + bb8[0], acc[i][1] + bb8[1], acc[i][2] + bb8[2], acc[i][3] + bb8[3]};
    float4 o1 = {acc[i][4] + bb8[4], acc[i][5] + bb8[5], acc[i][6] + bb8[6], acc[i][7] + bb8[7]};
    *(float4*)(out + (size_t)row * 1024 + bx * 128 + tx * 4) = o0;
    *(float4*)(out + (size_t)row * 1024 + bx * 128 + 64 + tx * 4) = o1;
  }
}

// ---------------------------------------------------------------------------
// 3/5. Recurrence. grid: (NCAND=64 candidates, 2 dirs), block 256.
// a) Election (R6, proven). b) Coherence probe (R6, proven).
// c) Steady state, ONE barrier per step:
//    row map: r=tid>>1, half=tid&1, g=r&3, kl=r>>2 -> the 8 lanes
//    8kl..8kl+7 of a wave hold all 4 gate rows (x2 halves) of h_kl.
//    FMA -> shfl_xor(1) half-combine -> +xg+bias (even lanes) -> 3 in-wave
//    shfl gathers -> lanes (tid&7)==0 do gates+publish (R6 packed rd_l2/
//    agent seqlock) -> all threads poll remote entries -> xnext store +
//    2-deep xg prefetch issued AFTER polls (rd_l2's vmcnt(0) no longer
//    drains an in-flight HBM load) -> hbuf[parity^1] -> ONE barrier.
// ---------------------------------------------------------------------------
__global__ __launch_bounds__(256) void recur_k(
    const float* __restrict__ xg_f, const float* __restrict__ xg_b,
    const float* __restrict__ Whh_f, const float* __restrict__ Whh_b,
    const float* __restrict__ bhh_f, const float* __restrict__ bhh_b,
    float* __restrict__ xnext, unsigned long long* __restrict__ hcomm_base,
    int* __restrict__ elect_base, unsigned long long* __restrict__ probe_base,
    int* __restrict__ vote_base) {
  int dir = blockIdx.y;         // 0=f, 1=b
  int tid = threadIdx.x;        // 0..255

  // ---- a) election -------------------------------------------------------
  int xcd;
  asm volatile("s_getreg_b32 %0, hwreg(HW_REG_XCC_ID)" : "=s"(xcd));
  xcd &= 7;
  int* cnt = elect_base + dir * (1 + NCAND);
  int* tab = cnt + 1;

  __shared__ int e_tab[NCAND];
  __shared__ int e_info[4];   // [0]=ticket, [1]=sel, [2]=kc, [3]=use_l2
  __shared__ int probe_ok[8];
  if (tid == 0) {
    int ticket = __hip_atomic_fetch_add(cnt, 1, __ATOMIC_RELAXED,
                                        __HIP_MEMORY_SCOPE_AGENT);
    __hip_atomic_store(&tab[ticket], xcd + 1, __ATOMIC_RELAXED,
                       __HIP_MEMORY_SCOPE_AGENT);
    e_info[0] = ticket;
  }
  if (tid < NCAND) {
    int v;
    do {
      v = __hip_atomic_load(&tab[tid], __ATOMIC_RELAXED,
                            __HIP_MEMORY_SCOPE_AGENT);
    } while (v == 0);
    e_tab[tid] = v - 1;
  }
  __syncthreads();
  if (tid == 0) {
    int ticket = e_info[0];
    int counts[8] = {0, 0, 0, 0, 0, 0, 0, 0};
    int home = -1;
    for (int i = 0; i < NCAND; i++) {
      int x = e_tab[i];
      counts[x]++;
      if (counts[x] == 8 && home < 0) home = x;
    }
    int sel = 0, kc = 0, probe = 0;
    if (home >= 0) {
      if (xcd == home) {
        int rank = 0;
        for (int i = 0; i < ticket; i++)
          if (e_tab[i] == home) rank++;
        if (rank < 8) { sel = 1; kc = rank; probe = 1; }
      }
    } else {
      if (ticket < 8) { sel = 1; kc = ticket; probe = 0; }
    }
    e_info[1] = sel; e_info[2] = kc; e_info[3] = probe;
  }
  __syncthreads();
  if (!e_info[1]) return;      // not selected: exit before loading weights
  int kc = e_info[2];
  int do_probe = e_info[3];
  int use_l2 = 0;

  // ---- b) coherence probe (bounded; decision via proven agent path) ------
  if (do_probe) {
    unsigned long long* probe = probe_base + (size_t)dir * 8 * 16;  // 128B/slot
    int* vote = vote_base + dir * 8;
    if (tid == 0) {
      pub_l2(&probe[kc * 16], 0xBEEF000000000000ull + (unsigned)kc);
    }
    if (tid < 8) {
      int found = 0;
      for (int iter = 0; iter < 3000 && !found; ++iter) {
        if (rd_l2(&probe[tid * 16]) ==
            0xBEEF000000000000ull + (unsigned)tid) found = 1;
      }
      probe_ok[tid] = found;
    }
    __syncthreads();
    if (tid == 0) {
      int ok = 1;
      for (int i = 0; i < 8; i++) ok &= probe_ok[i];
      // publish vote (1=fail, 2=pass) over the RELIABLE agent path
      __hip_atomic_store(&vote[kc], 1 + ok, __ATOMIC_RELAXED,
                         __HIP_MEMORY_SCOPE_AGENT);
    }
    if (tid < 8) {
      int v;
      do {
        v = __hip_atomic_load(&vote[tid], __ATOMIC_RELAXED,
                              __HIP_MEMORY_SCOPE_AGENT);
      } while (v == 0);   // bounded publishers => terminates
      probe_ok[tid] = v;
    }
    __syncthreads();
    if (tid == 0) {
      int all2 = 1;
      for (int i = 0; i < 8; i++) all2 &= (probe_ok[i] == 2);
      e_info[3] = all2;
    }
    __syncthreads();
    use_l2 = e_info[3];
  }

  // ---- c) setup ----------------------------------------------------------
  const float* Whh = dir ? Whh_b : Whh_f;
  const float* bhh = dir ? bhh_b : bhh_f;
  const float* xg = dir ? xg_b : xg_f;
  unsigned long long* hcomm = hcomm_base + (size_t)dir * 2 * HD;

  int r = tid >> 1;             // local row 0..127
  int half = tid & 1;           // which 128-col half
  int g = r & 3;                // gate 0..3 (i,f,g,o)  [NEW MAP]
  int kl = r >> 2;              // local h-index 0..31  [NEW MAP]
  int grow = g * 256 + kc * 32 + kl;  // global gate row 0..1023

  float4 Wv[32];
  const float4* wrow = (const float4*)(Whh + (size_t)grow * HD + half * 128);
#pragma unroll
  for (int j = 0; j < 32; j++) Wv[j] = wrow[j];
  float bias = bhh[grow];

  // h parity double-buffer: [2][272]; each 128-half padded +8 floats.
  __shared__ __align__(16) float hbuf[2][272];
  hbuf[0][tid] = 0.0f;
  if (tid < 16) hbuf[0][256 + tid] = 0.0f;

  float c = 0.0f;               // cell state (lanes tid&7==0 only)
  bool is_remote = ((tid >> 5) != kc);  // this thread polls entry `tid`
  bool is_prod = ((tid & 7) == 0);      // producer lane for h_{kl}
  int lanebase = (tid & 63) & ~7;       // 8-lane group base within wave

  // 2-deep xg prefetch (issued outside poll regions; consumed 2 steps later)
  float xn0 = 0.0f, xn1 = 0.0f;
  if (!half) {
    int ta = dir ? (T_LEN - 1) : 0;
    xn0 = xg[(size_t)ta * 1024 + grow];
    if (T_LEN > 1) {
      int tb = dir ? (T_LEN - 2) : 1;
      xn1 = xg[(size_t)tb * 1024 + grow];
    }
  }
  __syncthreads();

#pragma unroll 1
  for (int it = 0; it < T_LEN; ++it) {
    int t = dir ? (T_LEN - 1 - it) : it;
    int p = it & 1;             // hcomm parity
    int pr = it & 1;            // hbuf read parity
    unsigned int tag = (unsigned)(it + 1);

    float xgv = xn0;
    xn0 = xn1;

    const float4* h4 = (const float4*)(&hbuf[pr][0]) + half * 34;
    float4 acc = {0.f, 0.f, 0.f, 0.f};
#pragma unroll
    for (int j = 0; j < 32; j++) {
      float4 hv = h4[j];
      acc.x += Wv[j].x * hv.x;
      acc.y += Wv[j].y * hv.y;
      acc.z += Wv[j].z * hv.z;
      acc.w += Wv[j].w * hv.w;
    }
    float s = (acc.x + acc.y) + (acc.z + acc.w);
    s += __shfl_xor(s, 1, 64);   // combine the two halves of the row
    // full row value on even lanes: add xg + bias there
    float sf = half ? 0.0f : (s + xgv + bias);
    // gather the 4 gate values of h_kl into the producer lane (all in-wave)
    float zf = __shfl(sf, lanebase + 2, 64);
    float zg = __shfl(sf, lanebase + 4, 64);
    float zo = __shfl(sf, lanebase + 6, 64);

    float h = 0.0f;
    if (is_prod) {
      float zi = sf;
      c = fsig(zf) * c + fsig(zi) * ftanh(zg);
      h = fsig(zo) * ftanh(c);
      union { float f; unsigned u; } cv;
      cv.f = h;
      unsigned long long pkt = ((unsigned long long)tag << 32) | cv.u;
      int e = kc * 32 + kl;
      // publish FIRST (critical path). PACKED slots (R6-proven).
      if (use_l2) {
        pub_l2(&hcomm[p * HD + e], pkt);
      } else {
        __hip_atomic_store(&hcomm[p * HD + e], pkt,
                           __ATOMIC_RELAXED, __HIP_MEMORY_SCOPE_AGENT);
      }
      hbuf[pr ^ 1][((e >> 7) * 136) + (e & 127)] = h;
    }
    // poll remote entries: one thread per entry; payload arrives with the
    // successful poll (single L2 round trip, fully parallel).
    if (is_remote) {
      unsigned long long v;
      if (use_l2) {
        do { v = rd_l2(&hcomm[p * HD + tid]); } while ((unsigned)(v >> 32) != tag);
      } else {
        do {
          v = __hip_atomic_load(&hcomm[p * HD + tid], __ATOMIC_RELAXED,
                                __HIP_MEMORY_SCOPE_AGENT);
        } while ((unsigned)(v >> 32) != tag);
      }
      union { unsigned u; float f; } cv;
      cv.u = (unsigned)v;
      hbuf[pr ^ 1][((tid >> 7) * 136) + (tid & 127)] = cv.f;
    }
    // post-poll region: no vmcnt(0) until next step's polls -> these loads/
    // stores get a full step of latency cover.
    if (is_prod) {
      xnext[(size_t)t * DMODEL + dir * HD + kc * 32 + kl] = h;
    }
    if (!half && it + 2 < T_LEN) {
      int tn = dir ? (T_LEN - 3 - it) : (it + 2);
      xn1 = xg[(size_t)tn * 1024 + grow];
    }
    __syncthreads();             // h_t complete in hbuf[pr^1]
  }
}

// ---------------------------------------------------------------------------
// 6. Projection: feats[t][n] = x2[t][:] . W_out[n][:] + b_out[n]
// ---------------------------------------------------------------------------
__global__ void proj_k(const float* __restrict__ x2,
                       const float* __restrict__ Wo,
                       const float* __restrict__ bo,
                       float* __restrict__ feats) {
  int t = blockIdx.x;
  int tid = threadIdx.x;
  int n = tid & 31;
  int seg = tid >> 5;   // 0..7
  __shared__ float red[8][32];
  float s = 0.0f;
  if (n < NTAGS) {
    const float* xr = x2 + (size_t)t * DMODEL + seg * 64;
    const float* wr = Wo + (size_t)n * DMODEL + seg * 64;
#pragma unroll
    for (int j = 0; j < 64; j++) s += xr[j] * wr[j];
  }
  red[seg][n] = s;
  __syncthreads();
  if (tid < NTAGS) {
    float tot = bo[tid];
#pragma unroll
    for (int k = 0; k < 8; k++) tot += red[k][tid];
    feats[(size_t)t * NTAGS + tid] = tot;
  }
}

// ---------------------------------------------------------------------------
// 7. Viterbi: single block, 64 threads (one wave).
// ---------------------------------------------------------------------------
__global__ void viterbi_k(const float* __restrict__ feats,
                          const float* __restrict__ tr,
                          float* __restrict__ out) {
  __shared__ float v[NTAGS];
  __shared__ unsigned char bp[T_LEN * NTAGS];  // 40KB
  __shared__ float term[NTAGS];
  int tid = threadIdx.x;

  float trrow[NTAGS];
  if (tid < NTAGS) {
#pragma unroll
    for (int p = 0; p < NTAGS; p++) trrow[p] = tr[tid * NTAGS + p];
    v[tid] = (tid == START_TAG) ? 0.0f : -10000.0f;
  }
  __syncthreads();

#pragma unroll 1
  for (int t = 0; t < T_LEN; t++) {
    float fv = 0.0f;
    if (tid < NTAGS) fv = feats[(size_t)t * NTAGS + tid];
    float best = -3.4e38f;
    int arg = 0;
    if (tid < NTAGS) {
#pragma unroll
      for (int p = 0; p < NTAGS; p++) {
        float sc = v[p] + trrow[p];
        if (sc > best) { best = sc; arg = p; }
      }
      bp[t * NTAGS + tid] = (unsigned char)arg;
    }
    __syncthreads();
    if (tid < NTAGS) v[tid] = best + fv;
    __syncthreads();
  }

  if (tid < NTAGS) term[tid] = v[tid] + tr[END_TAG * NTAGS + tid];
  __syncthreads();
  if (tid == 0) {
    float bs = term[0];
    int bi = 0;
    for (int p = 1; p < NTAGS; p++) {
      if (term[p] > bs) { bs = term[p]; bi = p; }
    }
    out[0] = bs;
    int tag = bi;
    for (int t = T_LEN - 1; t >= 0; t--) {
      out[1 + t] = (float)tag;
      tag = bp[t * NTAGS + tag];
    }
  }
}

// ---------------------------------------------------------------------------
// Launch
// ---------------------------------------------------------------------------
extern "C" void kernel_launch(void* const* d_in, const int* in_sizes, int n_in,
                              void* d_out, int out_size, void* d_ws, size_t ws_size,
                              hipStream_t stream) {
  const int* sent = (const int*)d_in[0];
  const float* emb = (const float*)d_in[1];
  const float* l0f_Wih = (const float*)d_in[2];
  const float* l0f_Whh = (const float*)d_in[3];
  const float* l0f_bih = (const float*)d_in[4];
  const float* l0f_bhh = (const float*)d_in[5];
  const float* l0b_Wih = (const float*)d_in[6];
  const float* l0b_Whh = (const float*)d_in[7];
  const float* l0b_bih = (const float*)d_in[8];
  const float* l0b_bhh = (const float*)d_in[9];
  const float* l1f_Wih = (const float*)d_in[10];
  const float* l1f_Whh = (const float*)d_in[11];
  const float* l1f_bih = (const float*)d_in[12];
  const float* l1f_bhh = (const float*)d_in[13];
  const float* l1b_Wih = (const float*)d_in[14];
  const float* l1b_Whh = (const float*)d_in[15];
  const float* l1b_bih = (const float*)d_in[16];
  const float* l1b_bhh = (const float*)d_in[17];
  const float* W_out = (const float*)d_in[18];
  const float* b_out = (const float*)d_in[19];
  const float* transitions = (const float*)d_in[20];

  char* ws = (char*)d_ws;
  size_t off = 0;
  float* x0 = (float*)(ws + off);  off += (size_t)T_LEN * DMODEL * 4;          // 4MB
  float* xgf = (float*)(ws + off); off += (size_t)T_LEN * 1024 * 4;            // 8MB
  float* xgb = (float*)(ws + off); off += (size_t)T_LEN * 1024 * 4;            // 8MB
  float* x1 = (float*)(ws + off);  off += (size_t)T_LEN * DMODEL * 4;          // 4MB
  float* x2 = (float*)(ws + off);  off += (size_t)T_LEN * DMODEL * 4;          // 4MB
  float* feats = (float*)(ws + off); off += (size_t)T_LEN * NTAGS * 4;

  // sync area (single contiguous memset)
  off = (off + 127) & ~(size_t)127;
  char* sync_area = ws + off;
  unsigned long long* hcomm0 = (unsigned long long*)(sync_area);          // 8KB
  unsigned long long* hcomm1 = (unsigned long long*)(sync_area + 8192);   // 8KB
  int* elect0 = (int*)(sync_area + 16384);                                // 2KB
  int* elect1 = (int*)(sync_area + 18432);                                // 2KB
  unsigned long long* probe0 = (unsigned long long*)(sync_area + 20480);  // 2KB
  unsigned long long* probe1 = (unsigned long long*)(sync_area + 22528);  // 2KB
  int* vote0 = (int*)(sync_area + 24576);                                 // 1KB
  int* vote1 = (int*)(sync_area + 25600);                                 // 1KB
  size_t sync_bytes = 26624;
  off += sync_bytes;

  float* outf = (float*)d_out;

  // zero all sync state (d_ws is re-poisoned to 0xAA before every launch)
  (void)hipMemsetAsync(sync_area, 0, sync_bytes, stream);

  embed_k<<<dim3(T_LEN), dim3(128), 0, stream>>>(sent, emb, x0);

  gemm_xg_k<<<dim3(8, 16, 2), dim3(256), 0, stream>>>(
      x0, l0f_Wih, l0b_Wih, l0f_bih, l0b_bih, xgf, xgb);

  recur_k<<<dim3(NCAND, 2), dim3(256), 0, stream>>>(
      xgf, xgb, l0f_Whh, l0b_Whh, l0f_bhh, l0b_bhh, x1, hcomm0, elect0,
      probe0, vote0);

  gemm_xg_k<<<dim3(8, 16, 2), dim3(256), 0, stream>>>(
      x1, l1f_Wih, l1b_Wih, l1f_bih, l1b_bih, xgf, xgb);

  recur_k<<<dim3(NCAND, 2), dim3(256), 0, stream>>>(
      xgf, xgb, l1f_Whh, l1b_Whh, l1f_bhh, l1b_bhh, x2, hcomm1, elect1,
      probe1, vote1);

  proj_k<<<dim3(T_LEN), dim3(256), 0, stream>>>(x2, W_out, b_out, feats);

  viterbi_k<<<dim3(1), dim3(64), 0, stream>>>(feats, transitions, outf);
}